// Round 9
// baseline (597.846 us; speedup 1.0000x reference)
//
#include <hip/hip_runtime.h>

// DMPNN encoder, MI355X bf16-MFMA, round 15: fused k_msg2+segsum3 (k_msg2f).
//
// Pipeline (pos-space; identities: fidx[p]=rev[eidx[p]], sidx[p]=dst[eidx[p]]
// (sorted), pidx[p]=posOf[fidx[p]] involution, eidx[pidx[p]]=fidx[p]):
//   k_init : persistent waves, Wi in LDS, e-layout @pidx[p] (hbuf[p]=h0(eidx[p]))
//   segsum1: sequential (e-layout)
//   k_msg1 : tmp[sidx[p]] - h0@p -> h1 f-layout @p   (hbuf[p]=h1(fidx[p]))
//   segsum2: gather rows pidx[seg]
//   k_msg2f: FUSED. Computes h2(eidx[p]) at pos row p:
//              h1 operand = hbuf[p] (SEQUENTIAL; h1[rev[eidx[p]]]=h1[fidx[p]]@p)
//              tmp1 node  = sidx[pidx[p]] (2-hop gather, prefetched)
//            Outputs are pos-ordered = sorted by node -> block-level segmented
//            reduction: 64x128 h2 tile staged in LDS (bf16, 68-u32 stride),
//            wave-0 column scan; interior node segments -> exclusive plain
//            stores to f32 tmp2F; first/last segment per block -> f32
//            atomicAdd (~3.2M total, <=2 writers/line; NOT r13's 102M storm).
//            h2 never written to global: -205MB write, -segsum3 (-205MB read).
//   k_out  : TF32 variant reads f32 tmp2F.
// Workspace: CSR temps aliased into tmp2F region; 266.8MB total with runtime
// guard -> exact round-14 fallback path (<=245.3MB) if ws too small.
//
// Weight channel permutation c(p) = (p&64) + 2*(p&15) + ((p>>4)&1) + 32*((p>>5)&1):
// acc pair (2a,2a+1) at lane ln = channels 32a+2ln, 32a+2ln+1; u32 col u holds
// channels 2u,2u+1 (natural order); f32 idx = 2*(u32 col).

typedef unsigned int u32;
typedef unsigned short u16;
using bf16x8 = __attribute__((ext_vector_type(8))) __bf16;
using f32x4  = __attribute__((ext_vector_type(4))) float;

#define NN 50000
#define NP 400000
#define NE 800000
#define AF 133
#define HID 128
#define ATU 68      // atomBf row stride in u32
#define KPU1 80     // Wi packed row stride in u32 (160 cols = 5 kc chunks)
#define WHU 64      // Wh packed row stride (u32) = 256 B rows
#define KPU3 148    // Wo packed row stride; 144 data u32 = 288 cols = 9 chunks
#define KC3 9
#define NCH 196     // scan chunks of 256 covering NN

__device__ __forceinline__ u16 f2bf(float f) {
    union { float f; u32 u; } x; x.f = f;
    u32 r = x.u + 0x7fffu + ((x.u >> 16) & 1u);   // RNE
    return (u16)(r >> 16);
}
__device__ __forceinline__ float bf2f(u16 b) {
    union { u32 u; float f; } x; x.u = ((u32)b) << 16;
    return x.f;
}
__device__ __forceinline__ float lo16(u32 v) { return bf2f((u16)v); }
__device__ __forceinline__ float hi16(u32 v) { return bf2f((u16)(v >> 16)); }
__device__ __forceinline__ u32 pack2(float a, float b) {
    return (u32)f2bf(a) | ((u32)f2bf(b) << 16);
}
__device__ __forceinline__ float relu(float v) { return v > 0.f ? v : 0.f; }

// single-instruction RNE pack of two f32 -> packed bf16x2 (no builtin on gfx950)
__device__ __forceinline__ u32 cvt_pk_bf16(float lo, float hi) {
    u32 r;
    asm("v_cvt_pk_bf16_f32 %0, %1, %2" : "=v"(r) : "v"(lo), "v"(hi));
    return r;
}
__device__ __forceinline__ float bfLO(u32 v) {
    union { u32 u; float f; } x; x.u = v << 16; return x.f;
}
__device__ __forceinline__ float bfHI(u32 v) {
    union { u32 u; float f; } x; x.u = v & 0xffff0000u; return x.f;
}
__device__ __forceinline__ u32 sub2_pk(u32 t, u32 h) {
    return cvt_pk_bf16(bfLO(t) - bfLO(h), bfHI(t) - bfHI(h));
}
__device__ __forceinline__ u32 relu2_pk(float a, float b) {
    return cvt_pk_bf16(a > 0.f ? a : 0.f, b > 0.f ? b : 0.f);
}

union frag_cast { uint4 u; bf16x8 v; };

// ---------------- precompute kernels ----------------

__global__ void cvt_atom(const float* __restrict__ atom, u32* __restrict__ out) {
    int total = NN * ATU;
    for (int i = blockIdx.x * blockDim.x + threadIdx.x; i < total; i += gridDim.x * blockDim.x) {
        int n = i / ATU;
        int cu = i - n * ATU;
        int k = 2 * cu;
        float f0 = (k < AF) ? atom[n * AF + k] : 0.f;
        float f1 = (k + 1 < AF) ? atom[n * AF + k + 1] : 0.f;
        out[i] = pack2(f0, f1);
    }
}

__device__ __forceinline__ float wcol(const float* W, int n, int Kw, int len1, int off2, int len2, int k) {
    if (k < len1) return W[n * Kw + k];
    int j = k - off2;
    if (j >= 0 && j < len2) return W[n * Kw + len1 + j];
    return 0.f;
}
__global__ void cvt_w(const float* __restrict__ W, u32* __restrict__ out,
                      int Kw, int KpU, int len1, int off2, int len2) {
    int total = 128 * KpU;
    for (int i = blockIdx.x * blockDim.x + threadIdx.x; i < total; i += gridDim.x * blockDim.x) {
        int p = i / KpU;
        int cu = i - p * KpU;
        int t = p & 63;
        int c = (p & 64) + 2 * (t & 15) + ((t >> 4) & 1) + 32 * ((t >> 5) & 1);
        int k = 2 * cu;
        out[i] = pack2(wcol(W, c, Kw, len1, off2, len2, k),
                       wcol(W, c, Kw, len1, off2, len2, k + 1));
    }
}

// ---------------- CSR build ----------------

__global__ void hist(const int* __restrict__ dst, int* __restrict__ cnt) {
    for (int e = blockIdx.x * blockDim.x + threadIdx.x; e < NE; e += gridDim.x * blockDim.x)
        atomicAdd(&cnt[dst[e]], 1);
}

__global__ void scan1(const int* __restrict__ cnt, int* __restrict__ lexc, int* __restrict__ chunkSum) {
    __shared__ int s[256];
    int t = threadIdx.x, idx = blockIdx.x * 256 + t;
    int v = (idx < NN) ? cnt[idx] : 0;
    s[t] = v; __syncthreads();
    for (int off = 1; off < 256; off <<= 1) {
        int x = (t >= off) ? s[t - off] : 0;
        __syncthreads();
        s[t] += x;
        __syncthreads();
    }
    if (idx < NN) lexc[idx] = s[t] - v;
    if (t == 255) chunkSum[blockIdx.x] = s[255];
}

__global__ void scan2(const int* __restrict__ chunkSum, int* __restrict__ chunkOff) {
    __shared__ int s[256];
    int t = threadIdx.x;
    int v = (t < NCH) ? chunkSum[t] : 0;
    s[t] = v; __syncthreads();
    for (int off = 1; off < 256; off <<= 1) {
        int x = (t >= off) ? s[t - off] : 0;
        __syncthreads();
        s[t] += x;
        __syncthreads();
    }
    if (t < NCH) chunkOff[t] = s[t] - v;
}

__global__ void scan3(const int* __restrict__ lexc, const int* __restrict__ chunkOff,
                      int* __restrict__ rowptr, int* __restrict__ cursor) {
    int idx = blockIdx.x * 256 + threadIdx.x;
    if (idx < NN) {
        int v = lexc[idx] + chunkOff[blockIdx.x];
        rowptr[idx] = v;
        cursor[idx] = v;
    }
    if (idx == 0) rowptr[NN] = NE;
}

__global__ void scatter(const int* __restrict__ dst, const int* __restrict__ rev,
                        int* __restrict__ cursor, int* __restrict__ fidx,
                        int* __restrict__ sidx, int* __restrict__ posOf) {
    for (int e = blockIdx.x * blockDim.x + threadIdx.x; e < NE; e += gridDim.x * blockDim.x) {
        int d = dst[e];
        int pos = atomicAdd(&cursor[d], 1);
        fidx[pos] = rev[e];
        sidx[pos] = d;        // = src[fidx[pos]], nondecreasing over pos
        posOf[e] = pos;
    }
}

__global__ void pidx_build(const int* __restrict__ fidx, const int* __restrict__ posOf,
                           int* __restrict__ pidx) {
    for (int p = blockIdx.x * blockDim.x + threadIdx.x; p < NE; p += gridDim.x * blockDim.x)
        pidx[p] = posOf[fidx[p]];
}

// ---------------- segment sum ----------------
template<bool G>
__global__ __launch_bounds__(256)
void segsum_t(const int* __restrict__ rowptr, const int* __restrict__ gat,
              const u32* __restrict__ h, u32* __restrict__ tmp) {
    const int lane = threadIdx.x & 63;
    const int wv = threadIdx.x >> 6;
    const int rsel = lane >> 4;
    const int cg = lane & 15;
    const int nwaves = gridDim.x * 4;
    for (int n = blockIdx.x * 4 + wv; n < NN; n += nwaves) {
        int beg = rowptr[n], end = rowptr[n + 1];
        float a0 = 0, a1 = 0, a2 = 0, a3 = 0, a4 = 0, a5 = 0, a6 = 0, a7 = 0;
        int i = beg;
        for (; i + 8 <= end; i += 8) {
            int rA = G ? gat[i + rsel] : (i + rsel);
            int rB = G ? gat[i + 4 + rsel] : (i + 4 + rsel);
            uint4 hA = *(const uint4*)(h + (size_t)rA * 64 + 4 * cg);
            uint4 hB = *(const uint4*)(h + (size_t)rB * 64 + 4 * cg);
            a0 += lo16(hA.x) + lo16(hB.x); a1 += hi16(hA.x) + hi16(hB.x);
            a2 += lo16(hA.y) + lo16(hB.y); a3 += hi16(hA.y) + hi16(hB.y);
            a4 += lo16(hA.z) + lo16(hB.z); a5 += hi16(hA.z) + hi16(hB.z);
            a6 += lo16(hA.w) + lo16(hB.w); a7 += hi16(hA.w) + hi16(hB.w);
        }
        for (; i < end; i += 4) {
            if (i + rsel < end) {
                int rA = G ? gat[i + rsel] : (i + rsel);
                uint4 hA = *(const uint4*)(h + (size_t)rA * 64 + 4 * cg);
                a0 += lo16(hA.x); a1 += hi16(hA.x);
                a2 += lo16(hA.y); a3 += hi16(hA.y);
                a4 += lo16(hA.z); a5 += hi16(hA.z);
                a6 += lo16(hA.w); a7 += hi16(hA.w);
            }
        }
        a0 += __shfl_xor(a0, 16); a0 += __shfl_xor(a0, 32);
        a1 += __shfl_xor(a1, 16); a1 += __shfl_xor(a1, 32);
        a2 += __shfl_xor(a2, 16); a2 += __shfl_xor(a2, 32);
        a3 += __shfl_xor(a3, 16); a3 += __shfl_xor(a3, 32);
        a4 += __shfl_xor(a4, 16); a4 += __shfl_xor(a4, 32);
        a5 += __shfl_xor(a5, 16); a5 += __shfl_xor(a5, 32);
        a6 += __shfl_xor(a6, 16); a6 += __shfl_xor(a6, 32);
        a7 += __shfl_xor(a7, 16); a7 += __shfl_xor(a7, 32);
        if (rsel == 0) {
            uint4 o;
            o.x = pack2(a0, a1); o.y = pack2(a2, a3);
            o.z = pack2(a4, a5); o.w = pack2(a6, a7);
            *(uint4*)(tmp + (size_t)n * 64 + 4 * cg) = o;
        }
    }
}

// ---------------- k_init: persistent waves, VMEM-free MFMA loop ----------------
__global__ __launch_bounds__(256, 3)
void k_init(const u32* __restrict__ atomBf, const float* __restrict__ bond,
            const int* __restrict__ fidx, const int* __restrict__ sidx,
            const int* __restrict__ pidx, const u32* __restrict__ Wp,
            u32* __restrict__ hout)
{
    __shared__ u32 Wlds[128 * 96];   // 49152 B; phys slot = slot ^ (row&7)
    const int tid  = threadIdx.x;
    const int lane = tid & 63;
    const int wv   = tid >> 6;
    const int ln   = lane & 15;
    const int q    = lane >> 4;

    {
        const int row = tid >> 1;        // 128 rows, 2 threads/row
        const int half = tid & 1;        // 10 slots of 16 B each
        const int rx = row & 7;
        #pragma unroll
        for (int sl = 0; sl < 10; ++sl) {
            int L = half * 10 + sl;      // 0..19
            int P = L ^ rx;              // <= 23, fits 24-slot stride
            *(uint4*)(Wlds + row * 96 + P * 4) = *(const uint4*)(Wp + row * KPU1 + L * 4);
        }
    }
    __syncthreads();

    const int NT = NE / 16;              // 50000 tiles of 16 rows
    const int stride = gridDim.x * 4;
    int s = blockIdx.x * 4 + wv;
    if (s >= NT) return;

    uint4  rA[4];
    uint4  rA4;
    float2 b01, b23, b45, b67;
    int4   stA;

    {
        int p = s * 16 + ln;
        int sr = sidx[p];
        int fr = fidx[p];
        stA = *(const int4*)(pidx + s * 16 + 4 * q);
        const u32* ab = atomBf + (size_t)sr * ATU;
        #pragma unroll
        for (int kc = 0; kc < 4; ++kc)
            rA[kc] = *(const uint4*)(ab + kc * 16 + q * 4);
        if (q == 0) rA4 = *(const uint4*)(ab + 64);
        const float* bp = bond + (size_t)fr * 14;
        if (q == 1) {
            b01 = *(const float2*)(bp + 0); b23 = *(const float2*)(bp + 2);
            b45 = *(const float2*)(bp + 4); b67 = *(const float2*)(bp + 6);
        } else if (q == 2) {
            b01 = *(const float2*)(bp + 8); b23 = *(const float2*)(bp + 10);
            b45 = *(const float2*)(bp + 12);
        }
    }

    while (true) {
        const int sn = s + stride;
        const bool more = sn < NT;       // wave-uniform

        int srB = 0, frB = 0;
        int4 stB;
        if (more) {
            int p = sn * 16 + ln;
            srB = sidx[p];
            frB = fidx[p];
            stB = *(const int4*)(pidx + sn * 16 + 4 * q);
        }

        bf16x8 aF[5];
        #pragma unroll
        for (int kc = 0; kc < 4; ++kc) { frag_cast fc; fc.u = rA[kc]; aF[kc] = fc.v; }
        {
            frag_cast f4;
            if (q == 0)      f4.u = rA4;
            else if (q == 1) f4.u = make_uint4(cvt_pk_bf16(b01.x, b01.y), cvt_pk_bf16(b23.x, b23.y),
                                               cvt_pk_bf16(b45.x, b45.y), cvt_pk_bf16(b67.x, b67.y));
            else if (q == 2) f4.u = make_uint4(cvt_pk_bf16(b01.x, b01.y), cvt_pk_bf16(b23.x, b23.y),
                                               cvt_pk_bf16(b45.x, b45.y), 0u);
            else             f4.u = make_uint4(0u, 0u, 0u, 0u);
            aF[4] = f4.v;
        }

        if (more) {
            const u32* ab = atomBf + (size_t)srB * ATU;
            #pragma unroll
            for (int kc = 0; kc < 4; ++kc)
                rA[kc] = *(const uint4*)(ab + kc * 16 + q * 4);
            if (q == 0) rA4 = *(const uint4*)(ab + 64);
            const float* bp = bond + (size_t)frB * 14;
            if (q == 1) {
                b01 = *(const float2*)(bp + 0); b23 = *(const float2*)(bp + 2);
                b45 = *(const float2*)(bp + 4); b67 = *(const float2*)(bp + 6);
            } else if (q == 2) {
                b01 = *(const float2*)(bp + 8); b23 = *(const float2*)(bp + 10);
                b45 = *(const float2*)(bp + 12);
            }
        }

        u32 zoff = 0;
        asm volatile("" : "+v"(zoff));   // defeat LICM: keep B ds_reads in-loop
        f32x4 acc[8] = {};
        #pragma unroll
        for (int kc = 0; kc < 5; ++kc) {
            const u32* wrow = Wlds + zoff + ln * 96 + (((kc * 4 + q) ^ (ln & 7)) << 2);
            #pragma unroll
            for (int j = 0; j < 8; ++j) {
                bf16x8 b = *(const bf16x8*)(wrow + j * 1536);   // +16 rows * 96 u32
                acc[j] = __builtin_amdgcn_mfma_f32_16x16x32_bf16(aF[kc], b, acc[j], 0, 0, 0);
            }
        }

        #pragma unroll
        for (int r = 0; r < 4; ++r) {
            int wrow = (r == 0) ? stA.x : (r == 1) ? stA.y : (r == 2) ? stA.z : stA.w;
            u32* orow = hout + (size_t)wrow * 64;
            #pragma unroll
            for (int a = 0; a < 4; ++a)
                orow[16 * a + ln] = relu2_pk(acc[2 * a][r], acc[2 * a + 1][r]);
        }

        if (!more) break;
        s = sn;
        stA = stB;
    }
}

// ---------------- k_msg: persistent waves, VMEM-free MFMA loop ----------------
template<bool USEIDX>
__global__ __launch_bounds__(256, 4)
void k_msg_t(const int* __restrict__ sidx, const int* __restrict__ pidx,
             const u32* __restrict__ Wp, const u32* __restrict__ tmp,
             u32* __restrict__ h)
{
    __shared__ u32 Wlds[128 * 64];   // 32 KB; slot phys = slot ^ (row&15)
    const int tid  = threadIdx.x;
    const int lane = tid & 63;
    const int wv   = tid >> 6;
    const int ln   = lane & 15;
    const int q    = lane >> 4;

    {
        const int row = tid >> 1;        // 128 rows, 2 threads/row
        const int half = tid & 1;        // 8 slots of 16 B each
        const int rx = row & 15;
        #pragma unroll
        for (int sl = 0; sl < 8; ++sl) {
            int L = half * 8 + sl;
            int P = L ^ rx;
            *(uint4*)(Wlds + row * 64 + P * 4) = *(const uint4*)(Wp + row * 64 + L * 4);
        }
    }
    __syncthreads();

    const int NT = NE / 16;              // 50000 tiles of 16 rows
    const int stride = gridDim.x * 4;
    int s = blockIdx.x * 4 + wv;
    if (s >= NT) return;

    int4  stA;
    uint4 tv[4], hv[4];

    {
        int p = s * 16 + ln;
        int sr = sidx[p];
        int hr = USEIDX ? pidx[p] : p;
        if (USEIDX) stA = *(const int4*)(pidx + s * 16 + 4 * q);
        const u32* tb = tmp + (size_t)sr * 64 + q * 4;
        const u32* hb = h   + (size_t)hr * 64 + q * 4;
        #pragma unroll
        for (int kc = 0; kc < 4; ++kc) {
            tv[kc] = *(const uint4*)(tb + kc * 16);
            hv[kc] = *(const uint4*)(hb + kc * 16);
        }
    }

    while (true) {
        const int sn = s + stride;
        const bool more = sn < NT;       // wave-uniform

        int srB = 0, hrB = 0;
        int4 stB;
        if (more) {
            int p = sn * 16 + ln;
            srB = sidx[p];
            hrB = USEIDX ? pidx[p] : p;
            if (USEIDX) stB = *(const int4*)(pidx + sn * 16 + 4 * q);
        }

        bf16x8 aF[4];
        #pragma unroll
        for (int kc = 0; kc < 4; ++kc) {
            frag_cast fc;
            fc.u.x = sub2_pk(tv[kc].x, hv[kc].x);
            fc.u.y = sub2_pk(tv[kc].y, hv[kc].y);
            fc.u.z = sub2_pk(tv[kc].z, hv[kc].z);
            fc.u.w = sub2_pk(tv[kc].w, hv[kc].w);
            aF[kc] = fc.v;
        }

        if (more) {
            const u32* tb = tmp + (size_t)srB * 64 + q * 4;
            const u32* hb = h   + (size_t)hrB * 64 + q * 4;
            #pragma unroll
            for (int kc = 0; kc < 4; ++kc) {
                tv[kc] = *(const uint4*)(tb + kc * 16);
                hv[kc] = *(const uint4*)(hb + kc * 16);
            }
        }

        u32 zoff = 0;
        asm volatile("" : "+v"(zoff));   // defeat LICM: keep B ds_reads in-loop
        f32x4 acc[8] = {};
        #pragma unroll
        for (int kc = 0; kc < 4; ++kc) {
            const u32* wrow = Wlds + zoff + ln * 64 + (((kc * 4 + q) ^ ln) << 2);
            #pragma unroll
            for (int j = 0; j < 8; ++j) {
                bf16x8 b = *(const bf16x8*)(wrow + j * 1024);
                acc[j] = __builtin_amdgcn_mfma_f32_16x16x32_bf16(aF[kc], b, acc[j], 0, 0, 0);
            }
        }

        #pragma unroll
        for (int r = 0; r < 4; ++r) {
            int wrow = USEIDX
                ? ((r == 0) ? stA.x : (r == 1) ? stA.y : (r == 2) ? stA.z : stA.w)
                : (s * 16 + 4 * q + r);
            u32* orow = h + (size_t)wrow * 64;
            #pragma unroll
            for (int a = 0; a < 4; ++a)
                orow[16 * a + ln] = relu2_pk(acc[2 * a][r], acc[2 * a + 1][r]);
        }

        if (!more) break;
        s = sn;
        if (USEIDX) stA = stB;
    }
}

// ---------------- k_msg2f: fused k_msg2 + segsum3 ----------------
// Block tile = 64 pos rows (4 waves x 16). Row p: h2(eidx[p]) =
// relu(Wh . (tmp1[sidx[pidx[p]]] - hbuf[p])). hbuf read SEQUENTIAL; no hbuf
// write. h2 staged bf16 in LDS (stride 68 u32 -> 2-way bank-free), then
// wave-0 segmented column scan by node (sidx[p] sorted over p): interior
// segments -> exclusive plain stores to tmp2F; first/last segment of block
// -> f32 atomicAdd (~3.2M total). tmp2F must be zeroed before launch.
__global__ __launch_bounds__(256, 3)
void k_msg2f(const int* __restrict__ sidx, const int* __restrict__ pidx,
             const u32* __restrict__ Wp, const u32* __restrict__ tmp1,
             const u32* __restrict__ h, float* __restrict__ tmp2F)
{
    __shared__ u32 Wlds[128 * 64];   // 32 KB
    __shared__ u32 Hs[64 * 68];      // 17408 B stage; total 50176 -> 3 blocks/CU
    const int tid  = threadIdx.x;
    const int lane = tid & 63;
    const int wv   = tid >> 6;
    const int ln   = lane & 15;
    const int q    = lane >> 4;

    {
        const int row = tid >> 1;
        const int half = tid & 1;
        const int rx = row & 15;
        #pragma unroll
        for (int sl = 0; sl < 8; ++sl) {
            int L = half * 8 + sl;
            int P = L ^ rx;
            *(uint4*)(Wlds + row * 64 + P * 4) = *(const uint4*)(Wp + row * 64 + L * 4);
        }
    }
    __syncthreads();

    const int NTB = NE / 64;         // 12500 block tiles, exact
    int tb = blockIdx.x;
    if (tb >= NTB) return;

    uint4 tv[4], hv[4];
    int ndA;                          // node of block row `lane`

    // ---- prologue (serial 2-hop once)
    {
        int p = tb * 64 + wv * 16 + ln;
        int pj = pidx[p];
        int sA = sidx[pj];
        ndA = sidx[tb * 64 + lane];
        const u32* tb0 = tmp1 + (size_t)sA * 64 + q * 4;
        const u32* hb  = h + (size_t)p * 64 + q * 4;
        #pragma unroll
        for (int kc = 0; kc < 4; ++kc) {
            tv[kc] = *(const uint4*)(tb0 + kc * 16);
            hv[kc] = *(const uint4*)(hb + kc * 16);
        }
    }

    while (true) {
        const int tbn = tb + gridDim.x;
        const bool more = tbn < NTB; // block-uniform

        // early next-tile loads: pidx hop + node ids (h rows after convert)
        int pjB = 0, ndB = 0;
        if (more) {
            int pn = tbn * 64 + wv * 16 + ln;
            pjB = pidx[pn];
            ndB = sidx[tbn * 64 + lane];
        }

        // convert current raw -> A fragments (frees tv/hv)
        bf16x8 aF[4];
        #pragma unroll
        for (int kc = 0; kc < 4; ++kc) {
            frag_cast fc;
            fc.u.x = sub2_pk(tv[kc].x, hv[kc].x);
            fc.u.y = sub2_pk(tv[kc].y, hv[kc].y);
            fc.u.z = sub2_pk(tv[kc].z, hv[kc].z);
            fc.u.w = sub2_pk(tv[kc].w, hv[kc].w);
            aF[kc] = fc.v;
        }

        // 2nd hop + sequential h prefetch (pjB landed during convert)
        int sAB = 0;
        if (more) {
            sAB = sidx[pjB];
            int pn = tbn * 64 + wv * 16 + ln;
            const u32* hb = h + (size_t)pn * 64 + q * 4;
            #pragma unroll
            for (int kc = 0; kc < 4; ++kc)
                hv[kc] = *(const uint4*)(hb + kc * 16);
        }

        // MFMA 16x128, K=128; B from LDS only
        u32 zoff = 0;
        asm volatile("" : "+v"(zoff));
        f32x4 acc[8] = {};
        #pragma unroll
        for (int kc = 0; kc < 4; ++kc) {
            const u32* wrow = Wlds + zoff + ln * 64 + (((kc * 4 + q) ^ ln) << 2);
            #pragma unroll
            for (int j = 0; j < 8; ++j) {
                bf16x8 b = *(const bf16x8*)(wrow + j * 1024);
                acc[j] = __builtin_amdgcn_mfma_f32_16x16x32_bf16(aF[kc], b, acc[j], 0, 0, 0);
            }
        }

        // late prefetch: tmp1 rows (sAB landed during MFMA); in flight across scan
        if (more) {
            const u32* tb0 = tmp1 + (size_t)sAB * 64 + q * 4;
            #pragma unroll
            for (int kc = 0; kc < 4; ++kc)
                tv[kc] = *(const uint4*)(tb0 + kc * 16);
        }

        // stage h2 (bf16-packed, same rounding as hbuf path) into LDS
        #pragma unroll
        for (int r = 0; r < 4; ++r) {
            int lrow = wv * 16 + 4 * q + r;
            #pragma unroll
            for (int a = 0; a < 4; ++a)
                Hs[lrow * 68 + 16 * a + ln] = relu2_pk(acc[2 * a][r], acc[2 * a + 1][r]);
        }
        __syncthreads();

        // wave-0 segmented column scan: lane = u32 col (channels 2*lane,2*lane+1)
        if (wv == 0) {
            float r0 = 0.f, r1 = 0.f;
            int cur = __shfl(ndA, 0);
            int segstart = 0;
            #pragma unroll 8
            for (int r = 0; r < 64; ++r) {
                int nr = __shfl(ndA, r);       // wave-uniform
                if (nr != cur) {
                    float* tgt = tmp2F + (size_t)cur * 128 + 2 * lane;
                    if (segstart == 0) { atomicAdd(tgt, r0); atomicAdd(tgt + 1, r1); }
                    else { *(float2*)tgt = make_float2(r0, r1); }   // exclusive
                    r0 = 0.f; r1 = 0.f; cur = nr; segstart = r;
                }
                u32 u = Hs[r * 68 + lane];
                r0 += bfLO(u); r1 += bfHI(u);
            }
            float* tgt = tmp2F + (size_t)cur * 128 + 2 * lane;      // trailing: shared
            atomicAdd(tgt, r0); atomicAdd(tgt + 1, r1);
        }
        __syncthreads();

        if (!more) break;
        tb = tbn;
        ndA = ndB;
    }
}

// ---------------- k_out: persistent 16-node tiles, VMEM-free MFMA loop ----------------
// TF32: tmp operand is the f32 tmp2F buffer (f32 idx = 2 * u32 col of bf16 path).
template<bool TF32>
__global__ __launch_bounds__(256, 2)
void k_out_p(const u32* __restrict__ atomBf, const u32* __restrict__ Wp,
             const u32* __restrict__ tmp, const float* __restrict__ tmpF,
             float* __restrict__ out)
{
    __shared__ u32 Wlds[128 * KPU3];   // 75776 B -> 2 blocks/CU
    const int tid  = threadIdx.x;
    const int lane = tid & 63;
    const int wv   = tid >> 6;
    const int ln   = lane & 15;
    const int q    = lane >> 4;

    {
        const int row = tid >> 1;        // 128 rows, 2 threads/row
        const int half = tid & 1;        // 18 slots of 16 B each
        #pragma unroll
        for (int sl = 0; sl < 18; ++sl) {
            int L = half * 18 + sl;      // 0..35
            *(uint4*)(Wlds + row * KPU3 + L * 4) = *(const uint4*)(Wp + row * KPU3 + L * 4);
        }
    }
    __syncthreads();

    const int NT = NN / 16;              // 3125 tiles of 16 nodes
    const int stride = gridDim.x * 4;
    int s = blockIdx.x * 4 + wv;
    if (s >= NT) return;

    uint4  ra[9];
    float4 rf[8];

    auto gather = [&](int ss) {
        int n = ss * 16 + ln;
        const u32* ab = atomBf + (size_t)n * ATU;
        #pragma unroll
        for (int kc = 0; kc < 4; ++kc)
            ra[kc] = *(const uint4*)(ab + kc * 16 + q * 4);
        if constexpr (TF32) {
            const float* tf = tmpF + (size_t)n * 128;
            if (q == 0) {
                ra[4] = *(const uint4*)(ab + 64);
                rf[0] = *(const float4*)(tf + 24);  rf[1] = *(const float4*)(tf + 28);
                rf[2] = *(const float4*)(tf + 56);  rf[3] = *(const float4*)(tf + 60);
                rf[4] = *(const float4*)(tf + 88);  rf[5] = *(const float4*)(tf + 92);
                rf[6] = *(const float4*)(tf + 120); rf[7] = *(const float4*)(tf + 124);
            } else {
                rf[0] = *(const float4*)(tf + 8 * (q - 1));     rf[1] = *(const float4*)(tf + 8 * (q - 1) + 4);
                rf[2] = *(const float4*)(tf + 24 + 8 * q);      rf[3] = *(const float4*)(tf + 24 + 8 * q + 4);
                rf[4] = *(const float4*)(tf + 56 + 8 * q);      rf[5] = *(const float4*)(tf + 56 + 8 * q + 4);
                rf[6] = *(const float4*)(tf + 88 + 8 * q);      rf[7] = *(const float4*)(tf + 88 + 8 * q + 4);
            }
        } else {
            const u32* tp = tmp + (size_t)n * 64;
            if (q == 0) {
                ra[4] = *(const uint4*)(ab + 64);
                ra[5] = *(const uint4*)(tp + 12);
                ra[6] = *(const uint4*)(tp + 28);
                ra[7] = *(const uint4*)(tp + 44);
                ra[8] = *(const uint4*)(tp + 60);
            } else {
                ra[4] = *(const uint4*)(tp + (q - 1) * 4);
                ra[5] = *(const uint4*)(tp + 12 + q * 4);
                ra[6] = *(const uint4*)(tp + 28 + q * 4);
                ra[7] = *(const uint4*)(tp + 44 + q * 4);
                ra[8] = make_uint4(0u, 0u, 0u, 0u);
            }
        }
    };

    auto pk2q = [](float4 a, float4 b) {
        frag_cast fc;
        fc.u = make_uint4(cvt_pk_bf16(a.x, a.y), cvt_pk_bf16(a.z, a.w),
                          cvt_pk_bf16(b.x, b.y), cvt_pk_bf16(b.z, b.w));
        return fc.v;
    };

    gather(s);

    while (true) {
        const int sn = s + stride;
        const bool more = sn < NT;       // wave-uniform

        bf16x8 aF[9];
        #pragma unroll
        for (int kc = 0; kc < 4; ++kc) { frag_cast fc; fc.u = ra[kc]; aF[kc] = fc.v; }
        if constexpr (TF32) {
            frag_cast f4; f4.u = ra[4];
            frag_cast fz; fz.u = make_uint4(0u, 0u, 0u, 0u);
            aF[4] = (q == 0) ? f4.v : pk2q(rf[0], rf[1]);
            aF[5] = (q == 0) ? pk2q(rf[0], rf[1]) : pk2q(rf[2], rf[3]);
            aF[6] = (q == 0) ? pk2q(rf[2], rf[3]) : pk2q(rf[4], rf[5]);
            aF[7] = (q == 0) ? pk2q(rf[4], rf[5]) : pk2q(rf[6], rf[7]);
            aF[8] = (q == 0) ? pk2q(rf[6], rf[7]) : fz.v;
        } else {
            #pragma unroll
            for (int kc = 4; kc < 9; ++kc) { frag_cast fc; fc.u = ra[kc]; aF[kc] = fc.v; }
        }

        if (more) gather(sn);            // prefetch rides through MFMA (LDS B)

        u32 zoff = 0;
        asm volatile("" : "+v"(zoff));
        f32x4 acc[8] = {};
        #pragma unroll
        for (int kc = 0; kc < KC3; ++kc) {
            const u32* wrow = Wlds + zoff + ln * KPU3 + (kc * 4 + q) * 4;
            #pragma unroll
            for (int j = 0; j < 8; ++j) {
                bf16x8 b = *(const bf16x8*)(wrow + j * (16 * KPU3));
                acc[j] = __builtin_amdgcn_mfma_f32_16x16x32_bf16(aF[kc], b, acc[j], 0, 0, 0);
            }
        }

        #pragma unroll
        for (int r = 0; r < 4; ++r) {
            int n = s * 16 + 4 * q + r;
            float2* orow = (float2*)(out + (size_t)n * HID);
            #pragma unroll
            for (int a = 0; a < 4; ++a) {
                float2 v;
                v.x = relu(acc[2 * a][r]);
                v.y = relu(acc[2 * a + 1][r]);
                orow[16 * a + ln] = v;
            }
        }

        if (!more) break;
        s = sn;
    }
}

// ---------------- launch ----------------

extern "C" void kernel_launch(void* const* d_in, const int* in_sizes, int n_in,
                              void* d_out, int out_size, void* d_ws, size_t ws_size,
                              hipStream_t stream) {
    const float* atom = (const float*)d_in[0];   // [50000][133]
    const float* bond = (const float*)d_in[1];   // [800000][14]
    const float* Wi   = (const float*)d_in[2];   // [128][147]
    const float* Wh   = (const float*)d_in[3];   // [128][128]
    const float* Wo   = (const float*)d_in[4];   // [128][261]
    const int*   src  = (const int*)d_in[5]; (void)src;
    const int*   dst  = (const int*)d_in[6];
    const int*   rev  = (const int*)d_in[7];
    float* out = (float*)d_out;

    char* ws = (char*)d_ws;
    size_t off = 0;
    auto take = [&](size_t bytes) { char* p = ws + off; off = (off + bytes + 255) & ~(size_t)255; return p; };
    // persistent prefix (fallback path touches only this + X's first 4 MB)
    u32* hbuf   = (u32*)take((size_t)NE * 64 * 4);     // 204.8 MB
    u32* tmp    = (u32*)take((size_t)NN * 64 * 4);     // 12.8 MB (bf16 segsum out)
    u32* atomBf = (u32*)take((size_t)NN * ATU * 4);    // 13.6 MB
    int* fidx   = (int*)take((size_t)NE * 4);
    int* sidx   = (int*)take((size_t)NE * 4);
    int* pidx   = (int*)take((size_t)NE * 4);
    int* rowptr = (int*)take((size_t)(NN + 1) * 4);
    u32* WiP = (u32*)take(128 * KPU1 * 4);
    u32* WhP = (u32*)take(128 * WHU * 4);
    u32* WoP = (u32*)take(128 * KPU3 * 4);
    char* X  = take((size_t)NN * 128 * 4);             // 25.6 MB, time-shared
    const size_t totalFused = off;                     // ~266.8 MB
    // X aliases (disjoint in time): CSR temps (dead after pidx_build) -> tmp2F
    int* posOf    = (int*)(X);
    int* cnt      = (int*)(X + 3200000);
    int* lexc     = (int*)(X + 3400192);
    int* cursor   = (int*)(X + 3600384);
    int* chunkSum = (int*)(X + 3800576);
    int* chunkOff = (int*)(X + 3801856);
    float* tmp2F  = (float*)X;

    const bool fused = (totalFused <= ws_size);

    cvt_atom<<<2048, 256, 0, stream>>>(atom, atomBf);
    cvt_w<<<48, 256, 0, stream>>>(Wi, WiP, 147, KPU1, 133, 136, 14);
    cvt_w<<<32, 256, 0, stream>>>(Wh, WhP, 128, WHU, 128, 1 << 20, 0);
    cvt_w<<<80, 256, 0, stream>>>(Wo, WoP, 261, KPU3, 133, 136, 128);

    hipMemsetAsync(cnt, 0, (size_t)NN * 4, stream);
    hist<<<1024, 256, 0, stream>>>(dst, cnt);
    scan1<<<NCH, 256, 0, stream>>>(cnt, lexc, chunkSum);
    scan2<<<1, 256, 0, stream>>>(chunkSum, chunkOff);
    scan3<<<NCH, 256, 0, stream>>>(lexc, chunkOff, rowptr, cursor);
    scatter<<<1024, 256, 0, stream>>>(dst, rev, cursor, fidx, sidx, posOf);
    pidx_build<<<1024, 256, 0, stream>>>(fidx, posOf, pidx);
    if (fused)   // CSR temps in X dead now; zero X for the f32 accumulator
        hipMemsetAsync(X, 0, (size_t)NN * 128 * 4, stream);

    k_init<<<768, 256, 0, stream>>>(atomBf, bond, fidx, sidx, pidx, WiP, hbuf);   // e-layout
    segsum_t<false><<<2048, 256, 0, stream>>>(rowptr, nullptr, hbuf, tmp);        // sequential
    k_msg_t<false><<<1024, 256, 0, stream>>>(sidx, pidx, WhP, tmp, hbuf);         // all-stream -> f-layout
    segsum_t<true><<<2048, 256, 0, stream>>>(rowptr, pidx, hbuf, tmp);            // gather -> tmp1

    if (fused) {
        k_msg2f<<<768, 256, 0, stream>>>(sidx, pidx, WhP, tmp, hbuf, tmp2F);      // fused h2+segsum3
        k_out_p<true><<<512, 256, 0, stream>>>(atomBf, WoP, nullptr, tmp2F, out);
    } else {
        k_msg_t<true><<<1024, 256, 0, stream>>>(sidx, pidx, WhP, tmp, hbuf);      // e-layout
        segsum_t<false><<<2048, 256, 0, stream>>>(rowptr, nullptr, hbuf, tmp);    // sequential
        k_out_p<false><<<512, 256, 0, stream>>>(atomBf, WoP, tmp, nullptr, out);
    }
}